// Round 11
// baseline (34.344 us; speedup 1.0000x reference)
//
#include <hip/hip_runtime.h>

#define BB 64
#define TT 12
#define NL 2000
#define PP 20
#define CLS 2
#define BIGF 1.0e9f

#define TPB   256                 // 4 waves; (256,1) proven: ~156 VGPR, no spill
#define NWAVE 4
#define LPB   500                 // lines per block -> nitems ~250 on 256 lanes
#define NBLK  4                   // NL / LPB; blocks per batch
#define NBLOCKS (NBLK * BB)       // 256 blocks

// ws layout (uint32) — cross-block combining purely via device-scope atomics
// (r5/r6-proven coherent without fences; r4: threadfence = L2 flush, banned).
// Contention is SHAPED: distinct-address publishes; per-batch ticket 4-wide;
// global ticket 64-wide (r6's 512-wide single ticket ~26us -> the lesson).
//   mind2 : [t*BB + b]      atomicMax of ~bits(v)  (== float-min, init 0)
//   cmhas : [OFF_CMH + b]   atomicOr: bits 0..11 = cmask, bit 12 = has_lines
//   ctrb  : [OFF_CTRB + b]  per-batch ticket (4 contenders)
//   gctr  : [OFF_GCTR]      global ticket (64 contenders)
//   ws2   : [OFF_WS2 + 2b(+1)] batch (total,csum) — atomicExch'd, no init
#define OFF_CMH  (TT * BB)            // 768
#define OFF_CTRB (TT * BB + BB)       // 832
#define OFF_GCTR (TT * BB + 2 * BB)   // 896
#define OFF_WS2  (TT * BB + 2 * BB + 8)
#define MEMSET_U32 (TT * BB + 2 * BB + 1)   // 897 u32 = 3588 B
#define HASBIT (1u << 12)

__global__ __launch_bounds__(TPB, 1) void gtmb_fused(
    const float* __restrict__ pred,    // B,T,2
    const float* __restrict__ pts,     // B,N,1,P,2
    const int*   __restrict__ labels,  // B,N
    const float* __restrict__ masks,   // B,T
    unsigned int* __restrict__ ws,
    float* __restrict__ out) {
    const int b    = blockIdx.y;
    const int blk  = blockIdx.x;       // chunk of 500 lines
    const int tid  = threadIdx.x;
    const int lane = tid & 63, wave = tid >> 6;

    __shared__ unsigned short sidx[LPB];
    __shared__ int wcnt[NWAVE];
    __shared__ float sred[NWAVE][TT];
    __shared__ unsigned int scmw[NWAVE];

    // ---- trajectory loads issued first: latency hides under compaction ----
    float ex[TT], ey[TT];
    const float* pb = pred + b * (TT * 2);
#pragma unroll
    for (int t = 0; t < TT; ++t) { ex[t] = pb[2*t]; ey[t] = pb[2*t+1]; }

    // ---- phase 1: ballot compaction of valid lines (4-wave LDS prefix) ----
    const int base = blk * LPB;        // 500*blk: even -> int2-aligned
    int v0 = 0, v1 = 0, n0 = 0;
    if (tid < LPB / 2) {               // 250 int2 = 500 labels
        n0 = base + 2 * tid;
        int2 lb = *reinterpret_cast<const int2*>(labels + b * NL + n0);
        v0 = (lb.x == CLS);
        v1 = (lb.y == CLS);
    }
    unsigned long long m0 = __ballot(v0);
    unsigned long long m1 = __ballot(v1);
    unsigned long long lt = (1ull << lane) - 1ull;
    if (lane == 0) wcnt[wave] = __popcll(m0) + __popcll(m1);
    __syncthreads();
    int off = 0, cnt = 0;
#pragma unroll
    for (int w2 = 0; w2 < NWAVE; ++w2) {
        int c = wcnt[w2];
        if (w2 < wave) off += c;
        cnt += c;
    }
    const int c0 = __popcll(m0);
    if (v0) sidx[off + __popcll(m0 & lt)]      = (unsigned short)n0;
    if (v1) sidx[off + c0 + __popcll(m1 & lt)] = (unsigned short)(n0 + 1);
    __syncthreads();

    float mind2[TT];
#pragma unroll
    for (int t = 0; t < TT; ++t) mind2[t] = BIGF;
    unsigned int cmask = 0;

    // ---- phase 2: dense items, one half-line (10 pts / 10 segs) per item ----
    // nitems = 2*cnt ~ 250+-19 on 256 lanes -> ~98% density, single pass.
    const int nitems = 2 * cnt;
    for (int w = tid; w < nitems; w += TPB) {
        const int ln = sidx[w >> 1];
        const int h  = w & 1;
        const float4* lp = reinterpret_cast<const float4*>(
                               pts + (long)(b * NL + ln) * (PP * 2)) + h * 5;
        float4 q0 = lp[0], q1 = lp[1], q2 = lp[2], q3 = lp[3], q4 = lp[4];
        float p10x = q4.z, p10y = q4.w;          // h=1: dup of p9 (degenerate)
        if (h == 0) { float4 q5 = lp[5]; p10x = q5.x; p10y = q5.y; }

        float px[11], py[11];
        px[0]=q0.x; py[0]=q0.y;  px[1]=q0.z; py[1]=q0.w;
        px[2]=q1.x; py[2]=q1.y;  px[3]=q1.z; py[3]=q1.w;
        px[4]=q2.x; py[4]=q2.y;  px[5]=q2.z; py[5]=q2.w;
        px[6]=q3.x; py[6]=q3.y;  px[7]=q3.z; py[7]=q3.w;
        px[8]=q4.x; py[8]=q4.y;  px[9]=q4.z; py[9]=q4.w;
        px[10]=p10x; py[10]=p10y;

        // min distance^2: pts 0..9 (pt 10 is the next half's pt 0)
#pragma unroll
        for (int i = 0; i < 10; ++i) {
#pragma unroll
            for (int t = 0; t < TT; ++t) {
                float dx = px[i] - ex[t];
                float dy = py[i] - ey[t];
                mind2[t] = fminf(mind2[t], fmaf(dx, dx, dy * dy));
            }
        }

        // segment intersection: segs (i,i+1), i=0..9
#pragma unroll
        for (int i = 0; i < 10; ++i) {
            float dx2 = px[i+1] - px[i];
            float dy2 = py[i+1] - py[i];
#pragma unroll
            for (int t = 0; t < TT; ++t) {
                float sx = t ? ex[t-1] : 0.0f;
                float sy = t ? ey[t-1] : 0.0f;
                float dxt = ex[t] - sx;
                float dyt = ey[t] - sy;
                float rx = px[i] - sx;
                float ry = py[i] - sy;
                float det = dxt * dy2 - dx2 * dyt;
                float n1  = rx * dy2 - ry * dx2;
                float n2  = rx * dyt - ry * dxt;
                // sign-xor form: boolean-identical to
                //   det>0 ? (0<=n1<=det && 0<=n2<=det)
                //         : det<0 ? (det<=n1<=0 && det<=n2<=0) : false
                unsigned int sb = __float_as_uint(det) & 0x80000000u;
                float n1x = __uint_as_float(__float_as_uint(n1) ^ sb);
                float n2x = __uint_as_float(__float_as_uint(n2) ^ sb);
                float ad  = fabsf(det);
                bool hit = (n1x >= 0.0f) & (n1x <= ad) &
                           (n2x >= 0.0f) & (n2x <= ad) & (det != 0.0f);
                if (hit) cmask |= (1u << t);
            }
        }
    }

    // ---- wave64 reduce, cross-wave via LDS ----
#pragma unroll
    for (int t = 0; t < TT; ++t) {
        float v = mind2[t];
        for (int o = 32; o; o >>= 1) v = fminf(v, __shfl_xor(v, o));
        mind2[t] = v;
    }
    for (int o = 32; o; o >>= 1) cmask |= __shfl_xor(cmask, o);

    if (lane == 0) {
#pragma unroll
        for (int t = 0; t < TT; ++t) sred[wave][t] = mind2[t];
        scmw[wave] = cmask;
    }
    __syncthreads();
    if (wave != 0) return;             // tail is wave-0-only; no more barriers

    // ---- publish block partials: 13 distinct-address atomics (wave 0) ----
    if (lane < TT) {
        float v = sred[0][lane];
#pragma unroll
        for (int w2 = 1; w2 < NWAVE; ++w2) v = fminf(v, sred[w2][lane]);
        atomicMax(&ws[lane * BB + b], ~__float_as_uint(v));
    } else if (lane == 16) {
        unsigned int cm = scmw[0] | scmw[1] | scmw[2] | scmw[3];
        atomicOr(&ws[OFF_CMH + b], cm | (cnt ? HASBIT : 0u));
    }
    asm volatile("s_waitcnt vmcnt(0)" ::: "memory");   // wave-local drain only

    // ---- per-batch ticket: 4 contenders per address ----
    int old = 0;
    if (lane == 0) old = (int)atomicAdd(&ws[OFF_CTRB + b], 1u);
    old = __shfl(old, 0);
    if (old != NBLK - 1) return;
    __builtin_amdgcn_sched_barrier(0);  // keep tail out of the main loop

    // ---- batch epilogue (one wave per batch): read-back via no-op RMWs ----
    unsigned int raw = 0u, cmh = 0u;
    if (lane < TT) raw = atomicMax(&ws[lane * BB + b], 0u);   // returns old
    if (lane == 12) cmh = atomicOr(&ws[OFF_CMH + b], 0u);
    float mk = (lane < TT) ? masks[b * TT + lane] : 0.0f;
    cmh = __shfl(cmh, 12);
    const bool hl = (cmh & HASBIT) != 0;
    float total = 0.0f, csum = 0.0f;
    bool blocked = false;
#pragma unroll
    for (int t = 0; t < TT; ++t) {      // serial t-order == reference epilogue
        float m   = __uint_as_float(~__shfl((int)raw, t));
        float mkt = __shfl(mk, t);
        bool valid_t = (mkt >= 0.5f) && hl;
        bool trig = valid_t && ((cmh >> t) & 1u);
        blocked = blocked || trig;
        if (valid_t && !blocked) {
            total += fmaxf(1.0f - sqrtf(m), 0.0f);
            csum += 1.0f;
        }
    }
    if (lane == 0) {
        atomicExch(&ws[OFF_WS2 + 2 * b],     __float_as_uint(total));
        atomicExch(&ws[OFF_WS2 + 2 * b + 1], __float_as_uint(csum));
    }
    asm volatile("s_waitcnt vmcnt(0)" ::: "memory");

    // ---- global ticket: 64 contenders on one address (vs r6's 512) ----
    int g = 0;
    if (lane == 0) g = (int)atomicAdd(&ws[OFF_GCTR], 1u);
    g = __shfl(g, 0);
    if (g != BB - 1) return;

    // ---- global final (one wave): 64-batch butterfly sum ----
    float tb = __uint_as_float(atomicOr(&ws[OFF_WS2 + 2 * lane], 0u));
    float cb = __uint_as_float(atomicOr(&ws[OFF_WS2 + 2 * lane + 1], 0u));
    for (int o = 32; o; o >>= 1) {
        tb += __shfl_xor(tb, o);
        cb += __shfl_xor(cb, o);
    }
    if (lane == 0) out[0] = (cb == 0.0f) ? 0.0f : tb / fmaxf(cb, 1.0f);
}

extern "C" void kernel_launch(void* const* d_in, const int* in_sizes, int n_in,
                              void* d_out, int out_size, void* d_ws, size_t ws_size,
                              hipStream_t stream) {
    const float* pred   = (const float*)d_in[0];
    const float* pts    = (const float*)d_in[1];
    const int*   labels = (const int*)d_in[2];
    const float* masks  = (const float*)d_in[3];
    float* out = (float*)d_out;
    unsigned int* ws = (unsigned int*)d_ws;

    // init mind2/cmhas/tickets (ws2 needs none: Exch-before-gated-read).
    // 3.6 KB memset node, graph-capturable, DMA path.
    hipMemsetAsync(d_ws, 0, MEMSET_U32 * sizeof(unsigned int), stream);

    dim3 grid(NBLK, BB);
    gtmb_fused<<<grid, TPB, 0, stream>>>(pred, pts, labels, masks, ws, out);
}

// Round 12
// 27.913 us; speedup vs baseline: 1.2304x; 1.2304x over previous
//
#include <hip/hip_runtime.h>

#define BB 64
#define TT 12
#define NL 2000
#define PP 20
#define CLS 2
#define BIGF 1.0e9f

#define TPB   256                 // 4 waves; (256,1) proven: ~156 VGPR, no spill
#define NWAVE 4
#define LPB   500                 // lines per block -> nitems ~250 on 256 lanes
#define NBLK  4                   // NL / LPB
#define NSLOT NBLK

// ws layout (uint32 units), [t][s][b] so final reads coalesce over b:
//   mind2 : [(t*NSLOT + s)*BB + b]      (floats)
//   cmask : [OFF_CM  + s*BB + b]
//   cnt   : [OFF_CNT + s*BB + b]
// every slot written by exactly one block -> plain stores; kernel-boundary
// release/acquire gives cross-XCD visibility (r0-r2/r8 proven).
// Structure ledger (bench us): two-kernel 27.2 | NBLK=8 29.2 | slab 37.2 |
// fused: fence 64.7 / ticket 38.0 / hier-ticket 34.3 / 1blk-batch 53.6.
// Fused tail = serialized cross-XCD atomic RTs; 2nd kernel beats it.
#define OFF_CM  (TT * NSLOT * BB)
#define OFF_CNT (TT * NSLOT * BB + NSLOT * BB)
// total 3584 u32 = 14 KB of d_ws

__global__ __launch_bounds__(TPB, 1) void gtmb_main(
    const float* __restrict__ pred,    // B,T,2
    const float* __restrict__ pts,     // B,N,1,P,2
    const int*   __restrict__ labels,  // B,N
    unsigned int* __restrict__ ws) {
    const int b    = blockIdx.y;
    const int blk  = blockIdx.x;       // chunk of 500 lines
    const int tid  = threadIdx.x;
    const int lane = tid & 63, wave = tid >> 6;

    __shared__ unsigned short sidx[LPB];
    __shared__ int wcnt[NWAVE];
    __shared__ float sred[NWAVE][TT];
    __shared__ unsigned int scmw[NWAVE];

    // ---- phase 1: ballot compaction of valid lines (4-wave LDS prefix) ----
    const int base = blk * LPB;        // 500*blk: even -> int2-aligned
    int v0 = 0, v1 = 0, n0 = 0;
    if (tid < LPB / 2) {               // 250 int2 = 500 labels
        n0 = base + 2 * tid;
        int2 lb = *reinterpret_cast<const int2*>(labels + b * NL + n0);
        v0 = (lb.x == CLS);
        v1 = (lb.y == CLS);
    }
    unsigned long long m0 = __ballot(v0);
    unsigned long long m1 = __ballot(v1);
    unsigned long long lt = (1ull << lane) - 1ull;
    if (lane == 0) wcnt[wave] = __popcll(m0) + __popcll(m1);
    __syncthreads();
    int off = 0, cnt = 0;
#pragma unroll
    for (int w2 = 0; w2 < NWAVE; ++w2) {
        int c = wcnt[w2];
        if (w2 < wave) off += c;
        cnt += c;
    }
    const int c0 = __popcll(m0);
    if (v0) sidx[off + __popcll(m0 & lt)]      = (unsigned short)n0;
    if (v1) sidx[off + c0 + __popcll(m1 & lt)] = (unsigned short)(n0 + 1);
    __syncthreads();

    // ---- trajectory (block-uniform, compiler scalarizes) ----
    float ex[TT], ey[TT];
    const float* pb = pred + b * (TT * 2);
#pragma unroll
    for (int t = 0; t < TT; ++t) { ex[t] = pb[2*t]; ey[t] = pb[2*t+1]; }

    float mind2[TT];
#pragma unroll
    for (int t = 0; t < TT; ++t) mind2[t] = BIGF;
    unsigned int cmask = 0;

    // ---- phase 2: dense items, one half-line (10 pts / 10 segs) per item ----
    // nitems = 2*cnt ~ 250+-19 on 256 lanes -> ~98% density, single pass.
    const int nitems = 2 * cnt;
    for (int w = tid; w < nitems; w += TPB) {
        const int ln = sidx[w >> 1];
        const int h  = w & 1;
        const float4* lp = reinterpret_cast<const float4*>(
                               pts + (long)(b * NL + ln) * (PP * 2)) + h * 5;
        float4 q0 = lp[0], q1 = lp[1], q2 = lp[2], q3 = lp[3], q4 = lp[4];
        float p10x = q4.z, p10y = q4.w;          // h=1: dup of p9 (degenerate)
        if (h == 0) { float4 q5 = lp[5]; p10x = q5.x; p10y = q5.y; }

        float px[11], py[11];
        px[0]=q0.x; py[0]=q0.y;  px[1]=q0.z; py[1]=q0.w;
        px[2]=q1.x; py[2]=q1.y;  px[3]=q1.z; py[3]=q1.w;
        px[4]=q2.x; py[4]=q2.y;  px[5]=q2.z; py[5]=q2.w;
        px[6]=q3.x; py[6]=q3.y;  px[7]=q3.z; py[7]=q3.w;
        px[8]=q4.x; py[8]=q4.y;  px[9]=q4.z; py[9]=q4.w;
        px[10]=p10x; py[10]=p10y;

        // min distance^2: pts 0..9 (pt 10 is the next half's pt 0)
#pragma unroll
        for (int i = 0; i < 10; ++i) {
#pragma unroll
            for (int t = 0; t < TT; ++t) {
                float dx = px[i] - ex[t];
                float dy = py[i] - ey[t];
                mind2[t] = fminf(mind2[t], fmaf(dx, dx, dy * dy));
            }
        }

        // segment intersection: segs (i,i+1), i=0..9
#pragma unroll
        for (int i = 0; i < 10; ++i) {
            float dx2 = px[i+1] - px[i];
            float dy2 = py[i+1] - py[i];
#pragma unroll
            for (int t = 0; t < TT; ++t) {
                float sx = t ? ex[t-1] : 0.0f;
                float sy = t ? ey[t-1] : 0.0f;
                float dxt = ex[t] - sx;
                float dyt = ey[t] - sy;
                float rx = px[i] - sx;
                float ry = py[i] - sy;
                float det = dxt * dy2 - dx2 * dyt;
                float n1  = rx * dy2 - ry * dx2;
                float n2  = rx * dyt - ry * dxt;
                // sign-xor form: boolean-identical to
                //   det>0 ? (0<=n1<=det && 0<=n2<=det)
                //         : det<0 ? (det<=n1<=0 && det<=n2<=0) : false
                unsigned int sb = __float_as_uint(det) & 0x80000000u;
                float n1x = __uint_as_float(__float_as_uint(n1) ^ sb);
                float n2x = __uint_as_float(__float_as_uint(n2) ^ sb);
                float ad  = fabsf(det);
                bool hit = (n1x >= 0.0f) & (n1x <= ad) &
                           (n2x >= 0.0f) & (n2x <= ad) & (det != 0.0f);
                if (hit) cmask |= (1u << t);
            }
        }
    }

    // ---- wave64 reduce, cross-wave via LDS, one slot write per block ----
#pragma unroll
    for (int t = 0; t < TT; ++t) {
        float v = mind2[t];
        for (int o = 32; o; o >>= 1) v = fminf(v, __shfl_xor(v, o));
        mind2[t] = v;
    }
    for (int o = 32; o; o >>= 1) cmask |= __shfl_xor(cmask, o);

    if (lane == 0) {
#pragma unroll
        for (int t = 0; t < TT; ++t) sred[wave][t] = mind2[t];
        scmw[wave] = cmask;
    }
    __syncthreads();
    float* wf = (float*)ws;
    if (tid < TT) {
        float v = sred[0][tid];
#pragma unroll
        for (int w2 = 1; w2 < NWAVE; ++w2) v = fminf(v, sred[w2][tid]);
        wf[(tid * NSLOT + blk) * BB + b] = v;
    } else if (tid == 16) {
        unsigned int cm = scmw[0] | scmw[1] | scmw[2] | scmw[3];
        ws[OFF_CM + blk * BB + b] = cm;
    } else if (tid == 17) {
        ws[OFF_CNT + blk * BB + b] = (unsigned int)cnt;
    }
}

// 256-thread final (was 1024): 4 waves instead of 16 for ~3KB of useful
// reads; wave g reduces t=3g..3g+2 (pattern proven bit-correct in r5's
// fused epilogue). Identical read set + fmin/or orders -> bit-identical.
__global__ __launch_bounds__(256) void gtmb_final(
    const float* __restrict__ masks,   // B,T
    const unsigned int* __restrict__ ws,
    float* __restrict__ out) {
    const int tid = threadIdx.x;
    const int b = tid & 63, g = tid >> 6;   // g = wave id 0..3

    __shared__ float sm[TT * BB];
    __shared__ unsigned int scm[BB], shas[BB];

    const float* wf = (const float*)ws;
#pragma unroll
    for (int k = 0; k < 3; ++k) {           // wave g handles t = 3g..3g+2
        const int t = 3 * g + k;
        float m = BIGF;
#pragma unroll
        for (int s = 0; s < NSLOT; ++s)
            m = fminf(m, wf[(t * NSLOT + s) * BB + b]);
        sm[t * BB + b] = m;
    }
    if (g == 0) {
        unsigned int cm = 0;
#pragma unroll
        for (int s = 0; s < NSLOT; ++s) cm |= ws[OFF_CM + s * BB + b];
        scm[b] = cm;
    } else if (g == 1) {
        unsigned int has = 0;
#pragma unroll
        for (int s = 0; s < NSLOT; ++s) has |= ws[OFF_CNT + s * BB + b];
        shas[b] = has;
    }
    __syncthreads();

    if (tid < BB) {  // wave 0: thread = batch
        const bool hl = shas[b] != 0;
        const unsigned int cm = scm[b];
        float total = 0.0f, cnt = 0.0f;
        bool blocked = false;
#pragma unroll
        for (int t = 0; t < TT; ++t) {
            bool valid_t = (masks[b * TT + t] >= 0.5f) && hl;
            bool trig = valid_t && ((cm >> t) & 1u);
            blocked = blocked || trig;
            if (valid_t && !blocked) {
                float d = sqrtf(sm[t * BB + b]);
                total += fmaxf(1.0f - d, 0.0f);
                cnt += 1.0f;
            }
        }
        for (int o = 32; o; o >>= 1) {
            total += __shfl_xor(total, o);
            cnt   += __shfl_xor(cnt, o);
        }
        if (b == 0) out[0] = (cnt == 0.0f) ? 0.0f : total / fmaxf(cnt, 1.0f);
    }
}

extern "C" void kernel_launch(void* const* d_in, const int* in_sizes, int n_in,
                              void* d_out, int out_size, void* d_ws, size_t ws_size,
                              hipStream_t stream) {
    const float* pred   = (const float*)d_in[0];
    const float* pts    = (const float*)d_in[1];
    const int*   labels = (const int*)d_in[2];
    const float* masks  = (const float*)d_in[3];
    float* out = (float*)d_out;
    unsigned int* ws = (unsigned int*)d_ws;

    dim3 grid(NBLK, BB);
    gtmb_main<<<grid, TPB, 0, stream>>>(pred, pts, labels, ws);
    gtmb_final<<<1, 256, 0, stream>>>(masks, ws, out);
}

// Round 13
// 27.232 us; speedup vs baseline: 1.2611x; 1.0250x over previous
//
#include <hip/hip_runtime.h>

#define BB 64
#define TT 12
#define NL 2000
#define PP 20
#define CLS 2
#define BIGF 1.0e9f

#define TPB   256                 // 4 waves; (256,1) proven: ~156 VGPR, no spill
#define NWAVE 4
#define LPB   500                 // lines per block -> nitems ~250 on 256 lanes
#define NBLK  4                   // NL / LPB
#define NSLOT NBLK

// ===== FINAL FORM (session best: 27.24us, r8) =====
// Structure ledger (bench us):
//   two-kernel plain-store (THIS)        27.2-27.9  <- floor, noise +-0.4
//   two-kernel NBLK=8 (2 waves/SIMD)     29.2   (occupancy doesn't help)
//   two-kernel LDS slab stage            37.2   (+15MB stream = +10us)
//   fused threadfence ticket             64.7   (fence = per-block L2 flush)
//   fused flat 512-wide ticket           38.0   (512 same-addr RMWs ~26us)
//   fused hierarchical ticket            34.3   (~12us serialized atomic RTs)
//   fused 1-block-per-batch              53.6   (serial main, 2% occupancy)
// Floor decomposition: ~6-8us device work + ~20us 2-node launch overhead.
// Every fusion variant loses: a kernel boundary is the cheapest device-wide
// release/acquire on CDNA4 (no mbarrier/cluster analog).
// Register lesson: __launch_bounds__ min-waves>1 or TPB>=512 caps VGPR at
// 64-128 -> 30-50 dwords/thread scratch spill (13-68MB HBM write-back).
//
// ws layout (uint32 units), [t][s][b] so final reads coalesce over b:
//   mind2 : [(t*NSLOT + s)*BB + b]      (floats)
//   cmask : [OFF_CM  + s*BB + b]
//   cnt   : [OFF_CNT + s*BB + b]
// every slot written by exactly one block -> plain stores; kernel-boundary
// release/acquire gives cross-XCD visibility.
#define OFF_CM  (TT * NSLOT * BB)
#define OFF_CNT (TT * NSLOT * BB + NSLOT * BB)
// total 3584 u32 = 14 KB of d_ws

__global__ __launch_bounds__(TPB, 1) void gtmb_main(
    const float* __restrict__ pred,    // B,T,2
    const float* __restrict__ pts,     // B,N,1,P,2
    const int*   __restrict__ labels,  // B,N
    unsigned int* __restrict__ ws) {
    const int b    = blockIdx.y;
    const int blk  = blockIdx.x;       // chunk of 500 lines
    const int tid  = threadIdx.x;
    const int lane = tid & 63, wave = tid >> 6;

    __shared__ unsigned short sidx[LPB];
    __shared__ int wcnt[NWAVE];
    __shared__ float sred[NWAVE][TT];
    __shared__ unsigned int scmw[NWAVE];

    // ---- phase 1: ballot compaction of valid lines (4-wave LDS prefix) ----
    const int base = blk * LPB;        // 500*blk: even -> int2-aligned
    int v0 = 0, v1 = 0, n0 = 0;
    if (tid < LPB / 2) {               // 250 int2 = 500 labels
        n0 = base + 2 * tid;
        int2 lb = *reinterpret_cast<const int2*>(labels + b * NL + n0);
        v0 = (lb.x == CLS);
        v1 = (lb.y == CLS);
    }
    unsigned long long m0 = __ballot(v0);
    unsigned long long m1 = __ballot(v1);
    unsigned long long lt = (1ull << lane) - 1ull;
    if (lane == 0) wcnt[wave] = __popcll(m0) + __popcll(m1);
    __syncthreads();
    int off = 0, cnt = 0;
#pragma unroll
    for (int w2 = 0; w2 < NWAVE; ++w2) {
        int c = wcnt[w2];
        if (w2 < wave) off += c;
        cnt += c;
    }
    const int c0 = __popcll(m0);
    if (v0) sidx[off + __popcll(m0 & lt)]      = (unsigned short)n0;
    if (v1) sidx[off + c0 + __popcll(m1 & lt)] = (unsigned short)(n0 + 1);
    __syncthreads();

    // ---- trajectory (block-uniform, compiler scalarizes) ----
    float ex[TT], ey[TT];
    const float* pb = pred + b * (TT * 2);
#pragma unroll
    for (int t = 0; t < TT; ++t) { ex[t] = pb[2*t]; ey[t] = pb[2*t+1]; }

    float mind2[TT];
#pragma unroll
    for (int t = 0; t < TT; ++t) mind2[t] = BIGF;
    unsigned int cmask = 0;

    // ---- phase 2: dense items, one half-line (10 pts / 10 segs) per item ----
    // nitems = 2*cnt ~ 250+-19 on 256 lanes -> ~98% density, single pass.
    const int nitems = 2 * cnt;
    for (int w = tid; w < nitems; w += TPB) {
        const int ln = sidx[w >> 1];
        const int h  = w & 1;
        const float4* lp = reinterpret_cast<const float4*>(
                               pts + (long)(b * NL + ln) * (PP * 2)) + h * 5;
        float4 q0 = lp[0], q1 = lp[1], q2 = lp[2], q3 = lp[3], q4 = lp[4];
        float p10x = q4.z, p10y = q4.w;          // h=1: dup of p9 (degenerate)
        if (h == 0) { float4 q5 = lp[5]; p10x = q5.x; p10y = q5.y; }

        float px[11], py[11];
        px[0]=q0.x; py[0]=q0.y;  px[1]=q0.z; py[1]=q0.w;
        px[2]=q1.x; py[2]=q1.y;  px[3]=q1.z; py[3]=q1.w;
        px[4]=q2.x; py[4]=q2.y;  px[5]=q2.z; py[5]=q2.w;
        px[6]=q3.x; py[6]=q3.y;  px[7]=q3.z; py[7]=q3.w;
        px[8]=q4.x; py[8]=q4.y;  px[9]=q4.z; py[9]=q4.w;
        px[10]=p10x; py[10]=p10y;

        // min distance^2: pts 0..9 (pt 10 is the next half's pt 0)
#pragma unroll
        for (int i = 0; i < 10; ++i) {
#pragma unroll
            for (int t = 0; t < TT; ++t) {
                float dx = px[i] - ex[t];
                float dy = py[i] - ey[t];
                mind2[t] = fminf(mind2[t], fmaf(dx, dx, dy * dy));
            }
        }

        // segment intersection: segs (i,i+1), i=0..9
#pragma unroll
        for (int i = 0; i < 10; ++i) {
            float dx2 = px[i+1] - px[i];
            float dy2 = py[i+1] - py[i];
#pragma unroll
            for (int t = 0; t < TT; ++t) {
                float sx = t ? ex[t-1] : 0.0f;
                float sy = t ? ey[t-1] : 0.0f;
                float dxt = ex[t] - sx;
                float dyt = ey[t] - sy;
                float rx = px[i] - sx;
                float ry = py[i] - sy;
                float det = dxt * dy2 - dx2 * dyt;
                float n1  = rx * dy2 - ry * dx2;
                float n2  = rx * dyt - ry * dxt;
                // sign-xor form: boolean-identical to
                //   det>0 ? (0<=n1<=det && 0<=n2<=det)
                //         : det<0 ? (det<=n1<=0 && det<=n2<=0) : false
                unsigned int sb = __float_as_uint(det) & 0x80000000u;
                float n1x = __uint_as_float(__float_as_uint(n1) ^ sb);
                float n2x = __uint_as_float(__float_as_uint(n2) ^ sb);
                float ad  = fabsf(det);
                bool hit = (n1x >= 0.0f) & (n1x <= ad) &
                           (n2x >= 0.0f) & (n2x <= ad) & (det != 0.0f);
                if (hit) cmask |= (1u << t);
            }
        }
    }

    // ---- wave64 reduce, cross-wave via LDS, one slot write per block ----
#pragma unroll
    for (int t = 0; t < TT; ++t) {
        float v = mind2[t];
        for (int o = 32; o; o >>= 1) v = fminf(v, __shfl_xor(v, o));
        mind2[t] = v;
    }
    for (int o = 32; o; o >>= 1) cmask |= __shfl_xor(cmask, o);

    if (lane == 0) {
#pragma unroll
        for (int t = 0; t < TT; ++t) sred[wave][t] = mind2[t];
        scmw[wave] = cmask;
    }
    __syncthreads();
    float* wf = (float*)ws;
    if (tid < TT) {
        float v = sred[0][tid];
#pragma unroll
        for (int w2 = 1; w2 < NWAVE; ++w2) v = fminf(v, sred[w2][tid]);
        wf[(tid * NSLOT + blk) * BB + b] = v;
    } else if (tid == 16) {
        unsigned int cm = scmw[0] | scmw[1] | scmw[2] | scmw[3];
        ws[OFF_CM + blk * BB + b] = cm;
    } else if (tid == 17) {
        ws[OFF_CNT + blk * BB + b] = (unsigned int)cnt;
    }
}

__global__ __launch_bounds__(1024) void gtmb_final(
    const float* __restrict__ masks,   // B,T
    const unsigned int* __restrict__ ws,
    float* __restrict__ out) {
    const int tid = threadIdx.x;
    const int b = tid & 63, g = tid >> 6;   // g = wave id 0..15

    __shared__ float sm[TT * BB];
    __shared__ unsigned int scm[BB], shas[BB];

    const float* wf = (const float*)ws;
    if (g < TT) {
        float m = BIGF;
#pragma unroll
        for (int s = 0; s < NSLOT; ++s)
            m = fminf(m, wf[(g * NSLOT + s) * BB + b]);
        sm[g * BB + b] = m;
    } else if (g == 12) {
        unsigned int cm = 0;
#pragma unroll
        for (int s = 0; s < NSLOT; ++s) cm |= ws[OFF_CM + s * BB + b];
        scm[b] = cm;
    } else if (g == 13) {
        unsigned int has = 0;
#pragma unroll
        for (int s = 0; s < NSLOT; ++s) has |= ws[OFF_CNT + s * BB + b];
        shas[b] = has;
    }
    __syncthreads();

    if (tid < BB) {  // wave 0: thread = batch
        const bool hl = shas[b] != 0;
        const unsigned int cm = scm[b];
        float total = 0.0f, cnt = 0.0f;
        bool blocked = false;
#pragma unroll
        for (int t = 0; t < TT; ++t) {
            bool valid_t = (masks[b * TT + t] >= 0.5f) && hl;
            bool trig = valid_t && ((cm >> t) & 1u);
            blocked = blocked || trig;
            if (valid_t && !blocked) {
                float d = sqrtf(sm[t * BB + b]);
                total += fmaxf(1.0f - d, 0.0f);
                cnt += 1.0f;
            }
        }
        for (int o = 32; o; o >>= 1) {
            total += __shfl_xor(total, o);
            cnt   += __shfl_xor(cnt, o);
        }
        if (b == 0) out[0] = (cnt == 0.0f) ? 0.0f : total / fmaxf(cnt, 1.0f);
    }
}

extern "C" void kernel_launch(void* const* d_in, const int* in_sizes, int n_in,
                              void* d_out, int out_size, void* d_ws, size_t ws_size,
                              hipStream_t stream) {
    const float* pred   = (const float*)d_in[0];
    const float* pts    = (const float*)d_in[1];
    const int*   labels = (const int*)d_in[2];
    const float* masks  = (const float*)d_in[3];
    float* out = (float*)d_out;
    unsigned int* ws = (unsigned int*)d_ws;

    dim3 grid(NBLK, BB);
    gtmb_main<<<grid, TPB, 0, stream>>>(pred, pts, labels, ws);
    gtmb_final<<<1, 1024, 0, stream>>>(masks, ws, out);
}